// Round 10
// baseline (165.089 us; speedup 1.0000x reference)
//
#include <hip/hip_runtime.h>
#include <math.h>

#define F0 136
#define F1 68
#define F2 6
#define KP 160   // K padded to 5*32
#define NP 80    // N padded to 5*16

typedef __attribute__((ext_vector_type(8))) short short8v;
typedef __attribute__((ext_vector_type(4))) float f32x4;

__device__ inline float bf2f(unsigned short u) {
    union { unsigned int i; float f; } v; v.i = ((unsigned int)u) << 16; return v.f;
}
__device__ inline unsigned short f2bf(float f) {
    union { float f; unsigned int i; } v; v.f = f;
    unsigned int r = v.i + 0x7FFFu + ((v.i >> 16) & 1u);  // round-nearest-even
    return (unsigned short)(r >> 16);
}

// ================= in-degree histogram over dst =================
__global__ void k_hist(const int* __restrict__ dst, int* __restrict__ counts, int E) {
    int e = blockIdx.x * blockDim.x + threadIdx.x;
    if (e < E) atomicAdd(&counts[dst[e]], 1);
}

// ===== fused small prep: W1->bf16 col-major padded  +  graph segments =====
__global__ void k_misc(const float* __restrict__ W1, unsigned short* __restrict__ Wb,
                       const int* __restrict__ batch, int* __restrict__ gs, int N, int G) {
    int i = blockIdx.x * blockDim.x + threadIdx.x;
    if (i < NP * KP) {
        int c = i / KP, k = i - c * KP;
        float v = (c < F1 && k < F0) ? W1[k * F1 + c] : 0.0f;
        Wb[c * KP + k] = f2bf(v);
    }
    if (i < N) {
        int bi = batch[i];
        int bp = (i == 0) ? -1 : batch[i - 1];
        for (int g = bp + 1; g <= bi; g++) gs[g] = i;
        if (i == N - 1) {
            for (int g = bi + 1; g <= G; g++) gs[g] = N;
        }
    }
}

// ===== alloc: block-local scan + atomic block offset (ranges unordered) ====
__global__ __launch_bounds__(256) void k_alloc(const int* __restrict__ counts,
                                               int* __restrict__ row_start,
                                               int* __restrict__ cursor,
                                               float* __restrict__ dinv,
                                               int* __restrict__ total, int N) {
    __shared__ int s[256];
    __shared__ int sbase;
    int t = threadIdx.x;
    int base = blockIdx.x * 1024 + t * 4;
    int v[4], sum = 0;
#pragma unroll
    for (int u = 0; u < 4; u++) {
        int idx = base + u;
        v[u] = (idx < N) ? counts[idx] : 0;
        if (idx < N) dinv[idx] = rsqrtf((float)v[u] + 1.0f);  // self loop
        sum += v[u];
    }
    s[t] = sum;
    __syncthreads();
    for (int off = 1; off < 256; off <<= 1) {
        int y = (t >= off) ? s[t - off] : 0;
        __syncthreads();
        s[t] += y;
        __syncthreads();
    }
    if (t == 255) sbase = atomicAdd(total, s[255]);
    __syncthreads();
    int threadExcl = sbase + s[t] - sum;
    int run = 0;
#pragma unroll
    for (int u = 0; u < 4; u++) {
        int idx = base + u;
        if (idx < N) { row_start[idx] = threadExcl + run; cursor[idx] = threadExcl + run; }
        run += v[u];
    }
}

// ================= scatter edges into CSR (by dst), src index only =========
__global__ void k_scatter(const int* __restrict__ src, const int* __restrict__ dst,
                          int* __restrict__ cursor, int* __restrict__ ssrc, int E) {
    int e = blockIdx.x * blockDim.x + threadIdx.x;
    if (e >= E) return;
    int s = src[e], d = dst[e];
    int pos = atomicAdd(&cursor[d], 1);
    ssrc[pos] = s;
}

// ========== lin1 via MFMA: h1' = (x @ W1) * dinv, bf16, SPLIT layout =======
// main cols 0..63 -> h1a [N][64] (128B-aligned rows); cols 64..67 -> h1t [N][4]
__global__ __launch_bounds__(256) void k_lin1(const float* __restrict__ x,
                                              const unsigned short* __restrict__ Wb,
                                              const float* __restrict__ dinv,
                                              unsigned short* __restrict__ h1a,
                                              unsigned short* __restrict__ h1t, int N) {
    int tid  = threadIdx.x;
    int lane = tid & 63;
    int w    = tid >> 6;
    int rl   = lane & 15;
    int kg   = lane >> 4;
    int base = blockIdx.x * 64 + w * 16;
    int node = base + rl;
    int nodeClamp = node < N ? node : (N - 1);

    f32x4 acc[5];
#pragma unroll
    for (int t = 0; t < 5; t++) acc[t] = (f32x4){0.f, 0.f, 0.f, 0.f};

#pragma unroll
    for (int kt = 0; kt < 5; kt++) {
        int k0 = kt * 32 + kg * 8;
        short8v a;
        if (k0 < F0) {
            const float* xr = x + (size_t)nodeClamp * F0 + k0;
            float4 lo = *(const float4*)xr;
            float4 hi = *(const float4*)(xr + 4);
            a[0] = (short)f2bf(lo.x); a[1] = (short)f2bf(lo.y);
            a[2] = (short)f2bf(lo.z); a[3] = (short)f2bf(lo.w);
            a[4] = (short)f2bf(hi.x); a[5] = (short)f2bf(hi.y);
            a[6] = (short)f2bf(hi.z); a[7] = (short)f2bf(hi.w);
        } else {
            a = (short8v){0, 0, 0, 0, 0, 0, 0, 0};
        }
#pragma unroll
        for (int nt = 0; nt < 5; nt++) {
            int col = nt * 16 + rl;
            short8v b = *(const short8v*)&Wb[col * KP + k0];
            acc[nt] = __builtin_amdgcn_mfma_f32_16x16x32_bf16(a, b, acc[nt], 0, 0, 0);
        }
    }

    int orow0 = base + kg * 4;
    float dv[4];
#pragma unroll
    for (int j = 0; j < 4; j++) {
        int nr = orow0 + j;
        dv[j] = (nr < N) ? dinv[nr] : 0.0f;
    }
#pragma unroll
    for (int nt = 0; nt < 4; nt++) {   // cols 0..63 -> h1a
        int col = nt * 16 + rl;
#pragma unroll
        for (int j = 0; j < 4; j++) {
            int nr = orow0 + j;
            if (nr < N) h1a[(size_t)nr * 64 + col] = f2bf(acc[nt][j] * dv[j]);
        }
    }
    {   // cols 64..67 -> h1t
        int col = 64 + rl;
        if (col < F1) {
#pragma unroll
            for (int j = 0; j < 4; j++) {
                int nr = orow0 + j;
                if (nr < N) h1t[(size_t)nr * 4 + rl] = f2bf(acc[4][j] * dv[j]);
            }
        }
    }
}

// ===== fused: agg1 gather + bias/relu + @W2, PERSISTENT waves, no LDS ======
// 512 blocks x 4 waves = 8192 waves (full residency); each wave grid-strides
// over nodes. W2/b1 live in registers (loaded once per wave). No barriers.
__global__ __launch_bounds__(256) void k_gather1_lin2(const unsigned short* __restrict__ h1a,
                                                      const unsigned short* __restrict__ h1t,
                                                      const float* __restrict__ dinv,
                                                      const int* __restrict__ row_start,
                                                      const int* __restrict__ counts,
                                                      const int* __restrict__ ssrc,
                                                      const float* __restrict__ b1,
                                                      const float* __restrict__ W2,
                                                      float* __restrict__ h2p, int N) {
    int lane = threadIdx.x & 63;
    int wid = blockIdx.x * 4 + (threadIdx.x >> 6);
    int nwaves = gridDim.x * 4;

    bool hi = lane < (F1 - 64);
    int colhi = 64 + (lane & 3);

    // per-wave uniform register preload (amortized over all nodes of this wave)
    float b1self = b1[lane];
    float b1hi   = b1[colhi];
    float w2s[F2], w2h[F2];
#pragma unroll
    for (int c = 0; c < F2; c++) {
        w2s[c] = W2[lane * F2 + c];
        w2h[c] = W2[colhi * F2 + c];
    }

    for (int n = wid; n < N; n += nwaves) {
        float acc0 = bf2f(h1a[(size_t)n * 64 + lane]);
        float acct = (lane < 4) ? bf2f(h1t[(size_t)n * 4 + lane]) : 0.0f;

        int js = row_start[n];
        int deg = counts[n];

        for (int w0 = 0; w0 < deg; w0 += 64) {
            int wlen = deg - w0; wlen = wlen > 64 ? 64 : wlen;
            int li = lane < wlen ? lane : wlen - 1;
            int idxv = ssrc[js + w0 + li];      // one coalesced VMEM per window

            int u0 = 0;
            for (; u0 + 8 <= wlen; u0 += 8) {   // full 8-chunks, independent gathers
                int s[8];
#pragma unroll
                for (int u = 0; u < 8; u++) s[u] = __shfl(idxv, u0 + u, 64);
                float a[8];
#pragma unroll
                for (int u = 0; u < 8; u++) a[u] = bf2f(h1a[(size_t)s[u] * 64 + lane]);
#pragma unroll
                for (int u = 0; u < 8; u++) acc0 += a[u];
            }
            int rem = wlen - u0;
            if (rem > 0) {                      // predicated 8-chunk tail
                int s[8];
#pragma unroll
                for (int u = 0; u < 8; u++) {
                    int uu = (u < rem) ? (u0 + u) : u0;
                    s[u] = __shfl(idxv, uu, 64);
                }
                float a[8];
#pragma unroll
                for (int u = 0; u < 8; u++) a[u] = bf2f(h1a[(size_t)s[u] * 64 + lane]);
#pragma unroll
                for (int u = 0; u < 8; u++) acc0 += (u < rem) ? a[u] : 0.0f;
            }

            // tail cols 64..67: 16 edges per instruction
            for (int e0 = 0; e0 < wlen; e0 += 16) {
                int ee = e0 + (lane >> 2);
                bool val = ee < wlen;
                int s = __shfl(idxv, val ? ee : 0, 64);
                float tv = bf2f(h1t[(size_t)s * 4 + (lane & 3)]);
                acct += val ? tv : 0.0f;
            }
        }

        // reduce tail partials across the 16 lane-groups sharing (lane&3)
        float acctr = acct;
#pragma unroll
        for (int off = 4; off < 64; off <<= 1) acctr += __shfl_xor(acctr, off, 64);

        float d = dinv[n];
        float v0 = fmaf(acc0, d, b1self);            v0 = v0 > 0.0f ? v0 : 0.0f;
        float v1 = hi ? fmaf(acctr, d, b1hi) : 0.0f; v1 = v1 > 0.0f ? v1 : 0.0f;

        float p[F2];
#pragma unroll
        for (int c = 0; c < F2; c++) p[c] = v0 * w2s[c] + v1 * w2h[c];

#pragma unroll
        for (int off = 1; off < 64; off <<= 1) {
#pragma unroll
            for (int c = 0; c < F2; c++) p[c] += __shfl_xor(p[c], off, 64);
        }
        if (lane == 0) {
#pragma unroll
            for (int c = 0; c < F2; c++) h2p[(size_t)n * F2 + c] = p[c] * d;
        }
    }
}

// ================= gather2 + bias/relu + head -> ynode (NO atomics) ========
__global__ __launch_bounds__(256) void k_gather2(const float* __restrict__ h2p,
                                                 const float* __restrict__ dinv,
                                                 const int* __restrict__ row_start,
                                                 const int* __restrict__ counts,
                                                 const int* __restrict__ ssrc,
                                                 const float* __restrict__ b2,
                                                 const float* __restrict__ Wl,
                                                 const float* __restrict__ bl,
                                                 const float* __restrict__ Wl2,
                                                 const float* __restrict__ bl2,
                                                 float* __restrict__ ynode, int N) {
    int t = blockIdx.x * blockDim.x + threadIdx.x;
    int n = t >> 3;
    int l = t & 7;
    if (n >= N) return;

    float acc[F2] = {0, 0, 0, 0, 0, 0};
    if (l == 0) {  // self-loop term h2'[n]
        const float* sr = h2p + (size_t)n * F2;
        float2 p0 = *(const float2*)&sr[0];
        float2 p1 = *(const float2*)&sr[2];
        float2 p2 = *(const float2*)&sr[4];
        acc[0] = p0.x; acc[1] = p0.y;
        acc[2] = p1.x; acc[3] = p1.y;
        acc[4] = p2.x; acc[5] = p2.y;
    }

    int js = row_start[n];
    int je = js + counts[n];
    for (int j = js + l; j < je; j += 8) {
        int s = ssrc[j];
        const float* r = h2p + (size_t)s * F2;
        float2 p0 = *(const float2*)&r[0];
        float2 p1 = *(const float2*)&r[2];
        float2 p2 = *(const float2*)&r[4];
        acc[0] += p0.x; acc[1] += p0.y;
        acc[2] += p1.x; acc[3] += p1.y;
        acc[4] += p2.x; acc[5] += p2.y;
    }

#pragma unroll
    for (int off = 1; off < 8; off <<= 1) {
#pragma unroll
        for (int c = 0; c < F2; c++) acc[c] += __shfl_xor(acc[c], off, 8);
    }

    if (l == 0) {
        float d = dinv[n];
        float y = 0.0f;
#pragma unroll
        for (int c = 0; c < F2; c++) {
            float v = fmaf(acc[c], d, b2[c]);
            v = v > 0.0f ? v : 0.0f;
            float we = Wl[c * 3 + 0] * Wl2[0] + Wl[c * 3 + 1] * Wl2[1] + Wl[c * 3 + 2] * Wl2[2];
            y = fmaf(v, we, y);
        }
        float cnst = bl[0] * Wl2[0] + bl[1] * Wl2[1] + bl[2] * Wl2[2] + bl2[0];
        ynode[n] = y + cnst;
    }
}

// ================= pool: one block per graph, tree reduce + sigmoid ========
__global__ __launch_bounds__(256) void k_pool(const float* __restrict__ ynode,
                                              const int* __restrict__ gs,
                                              float* __restrict__ out, int G) {
    int g = blockIdx.x;
    int s0 = gs[g], e0 = gs[g + 1];
    int t = threadIdx.x;
    float a = 0.0f;
    for (int i = s0 + t; i < e0; i += 256) a += ynode[i];
#pragma unroll
    for (int off = 1; off < 64; off <<= 1) a += __shfl_xor(a, off, 64);
    __shared__ float sm[4];
    if ((t & 63) == 0) sm[t >> 6] = a;
    __syncthreads();
    if (t == 0) {
        float tot = sm[0] + sm[1] + sm[2] + sm[3];
        out[g] = 1.0f / (1.0f + expf(-tot));
    }
}

extern "C" void kernel_launch(void* const* d_in, const int* in_sizes, int n_in,
                              void* d_out, int out_size, void* d_ws, size_t ws_size,
                              hipStream_t stream) {
    const float* x     = (const float*)d_in[0];
    const int*   ei    = (const int*)d_in[1];
    const int*   batch = (const int*)d_in[2];
    const float* W1    = (const float*)d_in[3];
    const float* b1    = (const float*)d_in[4];
    const float* W2    = (const float*)d_in[5];
    const float* b2    = (const float*)d_in[6];
    const float* Wl    = (const float*)d_in[7];
    const float* bl    = (const float*)d_in[8];
    const float* Wl2   = (const float*)d_in[9];
    const float* bl2   = (const float*)d_in[10];
    float* out = (float*)d_out;

    int N = in_sizes[0] / F0;   // 50000
    int E = in_sizes[1] / 2;    // 512000
    int G = out_size;           // 512
    const int* src = ei;
    const int* dst = ei + E;

    char* ws = (char*)d_ws;
    size_t off = 0;
    auto alloc = [&](size_t bytes) {
        void* p = ws + off;
        off = (off + bytes + 255) & ~(size_t)255;
        return p;
    };
    int*   counts    = (int*)alloc((size_t)(N + 1) * 4);  // [N] = total counter
    int*   row_start = (int*)alloc((size_t)N * 4);
    int*   cursor    = (int*)alloc((size_t)N * 4);
    float* dinv      = (float*)alloc((size_t)N * 4);
    int*   ssrc      = (int*)alloc((size_t)E * 4);
    unsigned short* h1a = (unsigned short*)alloc((size_t)N * 64 * 2);  // 128B rows
    unsigned short* h1t = (unsigned short*)alloc((size_t)N * 4 * 2);   // tail cols
    float* h2p       = (float*)alloc((size_t)N * F2 * 4);
    float* ynode     = (float*)alloc((size_t)N * 4);
    int*   gs        = (int*)alloc((size_t)(G + 1) * 4);
    unsigned short* Wb = (unsigned short*)alloc((size_t)NP * KP * 2);

    const int B = 256;
    int nScanBlocks = (N + 1023) / 1024;   // 49

    hipMemsetAsync(counts, 0, (size_t)(N + 1) * 4, stream);
    k_hist<<<(E + B - 1) / B, B, 0, stream>>>(dst, counts, E);
    k_misc<<<(N + B - 1) / B, B, 0, stream>>>(W1, Wb, batch, gs, N, G);
    k_alloc<<<nScanBlocks, 256, 0, stream>>>(counts, row_start, cursor, dinv, counts + N, N);
    k_scatter<<<(E + B - 1) / B, B, 0, stream>>>(src, dst, cursor, ssrc, E);
    k_lin1<<<(N + 63) / 64, 256, 0, stream>>>(x, Wb, dinv, h1a, h1t, N);
    k_gather1_lin2<<<512, 256, 0, stream>>>(h1a, h1t, dinv, row_start, counts, ssrc,
                                            b1, W2, h2p, N);
    k_gather2<<<((N * 8) + B - 1) / B, B, 0, stream>>>(h2p, dinv, row_start, counts, ssrc,
                                                       b2, Wl, bl, Wl2, bl2, ynode, N);
    k_pool<<<G, 256, 0, stream>>>(ynode, gs, out, G);
}

// Round 11
// 137.054 us; speedup vs baseline: 1.2046x; 1.2046x over previous
//
#include <hip/hip_runtime.h>
#include <math.h>

#define F0 136
#define F1 68
#define F2 6
#define KP 160   // K padded to 5*32
#define NP 80    // N padded to 5*16

typedef __attribute__((ext_vector_type(8))) short short8v;
typedef __attribute__((ext_vector_type(4))) float f32x4;

__device__ inline float bf2f(unsigned short u) {
    union { unsigned int i; float f; } v; v.i = ((unsigned int)u) << 16; return v.f;
}
__device__ inline unsigned short f2bf(float f) {
    union { float f; unsigned int i; } v; v.f = f;
    unsigned int r = v.i + 0x7FFFu + ((v.i >> 16) & 1u);  // round-nearest-even
    return (unsigned short)(r >> 16);
}

// ================= in-degree histogram over dst =================
__global__ void k_hist(const int* __restrict__ dst, int* __restrict__ counts, int E) {
    int e = blockIdx.x * blockDim.x + threadIdx.x;
    if (e < E) atomicAdd(&counts[dst[e]], 1);
}

// ===== fused small prep: W1->bf16 col-major padded  +  graph segments =====
__global__ void k_misc(const float* __restrict__ W1, unsigned short* __restrict__ Wb,
                       const int* __restrict__ batch, int* __restrict__ gs, int N, int G) {
    int i = blockIdx.x * blockDim.x + threadIdx.x;
    if (i < NP * KP) {
        int c = i / KP, k = i - c * KP;
        float v = (c < F1 && k < F0) ? W1[k * F1 + c] : 0.0f;
        Wb[c * KP + k] = f2bf(v);
    }
    if (i < N) {
        int bi = batch[i];
        int bp = (i == 0) ? -1 : batch[i - 1];
        for (int g = bp + 1; g <= bi; g++) gs[g] = i;
        if (i == N - 1) {
            for (int g = bi + 1; g <= G; g++) gs[g] = N;
        }
    }
}

// ===== alloc: block-local scan + atomic block offset (ranges unordered) ====
__global__ __launch_bounds__(256) void k_alloc(const int* __restrict__ counts,
                                               int* __restrict__ row_start,
                                               int* __restrict__ cursor,
                                               float* __restrict__ dinv,
                                               int* __restrict__ total, int N) {
    __shared__ int s[256];
    __shared__ int sbase;
    int t = threadIdx.x;
    int base = blockIdx.x * 1024 + t * 4;
    int v[4], sum = 0;
#pragma unroll
    for (int u = 0; u < 4; u++) {
        int idx = base + u;
        v[u] = (idx < N) ? counts[idx] : 0;
        if (idx < N) dinv[idx] = rsqrtf((float)v[u] + 1.0f);  // self loop
        sum += v[u];
    }
    s[t] = sum;
    __syncthreads();
    for (int off = 1; off < 256; off <<= 1) {
        int y = (t >= off) ? s[t - off] : 0;
        __syncthreads();
        s[t] += y;
        __syncthreads();
    }
    if (t == 255) sbase = atomicAdd(total, s[255]);
    __syncthreads();
    int threadExcl = sbase + s[t] - sum;
    int run = 0;
#pragma unroll
    for (int u = 0; u < 4; u++) {
        int idx = base + u;
        if (idx < N) { row_start[idx] = threadExcl + run; cursor[idx] = threadExcl + run; }
        run += v[u];
    }
}

// ================= scatter edges into CSR (by dst), src index only =========
__global__ void k_scatter(const int* __restrict__ src, const int* __restrict__ dst,
                          int* __restrict__ cursor, int* __restrict__ ssrc, int E) {
    int e = blockIdx.x * blockDim.x + threadIdx.x;
    if (e >= E) return;
    int s = src[e], d = dst[e];
    int pos = atomicAdd(&cursor[d], 1);
    ssrc[pos] = s;
}

// ========== lin1 via MFMA: h1' = (x @ W1) * dinv, bf16, SPLIT layout =======
// main cols 0..63 -> h1a [N][64] (128B-aligned rows); cols 64..67 -> h1t [N][4]
__global__ __launch_bounds__(256) void k_lin1(const float* __restrict__ x,
                                              const unsigned short* __restrict__ Wb,
                                              const float* __restrict__ dinv,
                                              unsigned short* __restrict__ h1a,
                                              unsigned short* __restrict__ h1t, int N) {
    int tid  = threadIdx.x;
    int lane = tid & 63;
    int w    = tid >> 6;
    int rl   = lane & 15;
    int kg   = lane >> 4;
    int base = blockIdx.x * 64 + w * 16;
    int node = base + rl;
    int nodeClamp = node < N ? node : (N - 1);

    f32x4 acc[5];
#pragma unroll
    for (int t = 0; t < 5; t++) acc[t] = (f32x4){0.f, 0.f, 0.f, 0.f};

#pragma unroll
    for (int kt = 0; kt < 5; kt++) {
        int k0 = kt * 32 + kg * 8;
        short8v a;
        if (k0 < F0) {
            const float* xr = x + (size_t)nodeClamp * F0 + k0;
            float4 lo = *(const float4*)xr;
            float4 hi = *(const float4*)(xr + 4);
            a[0] = (short)f2bf(lo.x); a[1] = (short)f2bf(lo.y);
            a[2] = (short)f2bf(lo.z); a[3] = (short)f2bf(lo.w);
            a[4] = (short)f2bf(hi.x); a[5] = (short)f2bf(hi.y);
            a[6] = (short)f2bf(hi.z); a[7] = (short)f2bf(hi.w);
        } else {
            a = (short8v){0, 0, 0, 0, 0, 0, 0, 0};
        }
#pragma unroll
        for (int nt = 0; nt < 5; nt++) {
            int col = nt * 16 + rl;
            short8v b = *(const short8v*)&Wb[col * KP + k0];
            acc[nt] = __builtin_amdgcn_mfma_f32_16x16x32_bf16(a, b, acc[nt], 0, 0, 0);
        }
    }

    int orow0 = base + kg * 4;
    float dv[4];
#pragma unroll
    for (int j = 0; j < 4; j++) {
        int nr = orow0 + j;
        dv[j] = (nr < N) ? dinv[nr] : 0.0f;
    }
#pragma unroll
    for (int nt = 0; nt < 4; nt++) {   // cols 0..63 -> h1a
        int col = nt * 16 + rl;
#pragma unroll
        for (int j = 0; j < 4; j++) {
            int nr = orow0 + j;
            if (nr < N) h1a[(size_t)nr * 64 + col] = f2bf(acc[nt][j] * dv[j]);
        }
    }
    {   // cols 64..67 -> h1t
        int col = 64 + rl;
        if (col < F1) {
#pragma unroll
            for (int j = 0; j < 4; j++) {
                int nr = orow0 + j;
                if (nr < N) h1t[(size_t)nr * 4 + rl] = f2bf(acc[4][j] * dv[j]);
            }
        }
    }
}

// ===== fused: agg1 gather + bias/relu + @W2, PERSISTENT waves, no LDS ======
// 2048 blocks x 4 waves = 8192 waves = full chip residency (256 CU x 32 waves).
// Each wave grid-strides over ~6 nodes. W2/b1 in registers. No barriers.
__global__ __launch_bounds__(256) void k_gather1_lin2(const unsigned short* __restrict__ h1a,
                                                      const unsigned short* __restrict__ h1t,
                                                      const float* __restrict__ dinv,
                                                      const int* __restrict__ row_start,
                                                      const int* __restrict__ counts,
                                                      const int* __restrict__ ssrc,
                                                      const float* __restrict__ b1,
                                                      const float* __restrict__ W2,
                                                      float* __restrict__ h2p, int N) {
    int lane = threadIdx.x & 63;
    int wid = blockIdx.x * 4 + (threadIdx.x >> 6);
    int nwaves = gridDim.x * 4;

    bool hi = lane < (F1 - 64);
    int colhi = 64 + (lane & 3);

    // per-wave uniform register preload (amortized over this wave's nodes)
    float b1self = b1[lane];
    float b1hi   = b1[colhi];
    float w2s[F2], w2h[F2];
#pragma unroll
    for (int c = 0; c < F2; c++) {
        w2s[c] = W2[lane * F2 + c];
        w2h[c] = W2[colhi * F2 + c];
    }

    for (int n = wid; n < N; n += nwaves) {
        float acc0 = bf2f(h1a[(size_t)n * 64 + lane]);
        float acct = (lane < 4) ? bf2f(h1t[(size_t)n * 4 + lane]) : 0.0f;

        int js = row_start[n];
        int deg = counts[n];

        for (int w0 = 0; w0 < deg; w0 += 64) {
            int wlen = deg - w0; wlen = wlen > 64 ? 64 : wlen;
            int li = lane < wlen ? lane : wlen - 1;
            int idxv = ssrc[js + w0 + li];      // one coalesced VMEM per window

            int u0 = 0;
            for (; u0 + 8 <= wlen; u0 += 8) {   // full 8-chunks, independent gathers
                int s[8];
#pragma unroll
                for (int u = 0; u < 8; u++) s[u] = __shfl(idxv, u0 + u, 64);
                float a[8];
#pragma unroll
                for (int u = 0; u < 8; u++) a[u] = bf2f(h1a[(size_t)s[u] * 64 + lane]);
#pragma unroll
                for (int u = 0; u < 8; u++) acc0 += a[u];
            }
            int rem = wlen - u0;
            if (rem > 0) {                      // predicated 8-chunk tail
                int s[8];
#pragma unroll
                for (int u = 0; u < 8; u++) {
                    int uu = (u < rem) ? (u0 + u) : u0;
                    s[u] = __shfl(idxv, uu, 64);
                }
                float a[8];
#pragma unroll
                for (int u = 0; u < 8; u++) a[u] = bf2f(h1a[(size_t)s[u] * 64 + lane]);
#pragma unroll
                for (int u = 0; u < 8; u++) acc0 += (u < rem) ? a[u] : 0.0f;
            }

            // tail cols 64..67: 16 edges per instruction
            for (int e0 = 0; e0 < wlen; e0 += 16) {
                int ee = e0 + (lane >> 2);
                bool val = ee < wlen;
                int s = __shfl(idxv, val ? ee : 0, 64);
                float tv = bf2f(h1t[(size_t)s * 4 + (lane & 3)]);
                acct += val ? tv : 0.0f;
            }
        }

        // reduce tail partials across the 16 lane-groups sharing (lane&3)
        float acctr = acct;
#pragma unroll
        for (int off = 4; off < 64; off <<= 1) acctr += __shfl_xor(acctr, off, 64);

        float d = dinv[n];
        float v0 = fmaf(acc0, d, b1self);            v0 = v0 > 0.0f ? v0 : 0.0f;
        float v1 = hi ? fmaf(acctr, d, b1hi) : 0.0f; v1 = v1 > 0.0f ? v1 : 0.0f;

        float p[F2];
#pragma unroll
        for (int c = 0; c < F2; c++) p[c] = v0 * w2s[c] + v1 * w2h[c];

#pragma unroll
        for (int off = 1; off < 64; off <<= 1) {
#pragma unroll
            for (int c = 0; c < F2; c++) p[c] += __shfl_xor(p[c], off, 64);
        }
        if (lane == 0) {
#pragma unroll
            for (int c = 0; c < F2; c++) h2p[(size_t)n * F2 + c] = p[c] * d;
        }
    }
}

// ================= gather2 + bias/relu + head -> ynode (NO atomics) ========
__global__ __launch_bounds__(256) void k_gather2(const float* __restrict__ h2p,
                                                 const float* __restrict__ dinv,
                                                 const int* __restrict__ row_start,
                                                 const int* __restrict__ counts,
                                                 const int* __restrict__ ssrc,
                                                 const float* __restrict__ b2,
                                                 const float* __restrict__ Wl,
                                                 const float* __restrict__ bl,
                                                 const float* __restrict__ Wl2,
                                                 const float* __restrict__ bl2,
                                                 float* __restrict__ ynode, int N) {
    int t = blockIdx.x * blockDim.x + threadIdx.x;
    int n = t >> 3;
    int l = t & 7;
    if (n >= N) return;

    float acc[F2] = {0, 0, 0, 0, 0, 0};
    if (l == 0) {  // self-loop term h2'[n]
        const float* sr = h2p + (size_t)n * F2;
        float2 p0 = *(const float2*)&sr[0];
        float2 p1 = *(const float2*)&sr[2];
        float2 p2 = *(const float2*)&sr[4];
        acc[0] = p0.x; acc[1] = p0.y;
        acc[2] = p1.x; acc[3] = p1.y;
        acc[4] = p2.x; acc[5] = p2.y;
    }

    int js = row_start[n];
    int je = js + counts[n];
    for (int j = js + l; j < je; j += 8) {
        int s = ssrc[j];
        const float* r = h2p + (size_t)s * F2;
        float2 p0 = *(const float2*)&r[0];
        float2 p1 = *(const float2*)&r[2];
        float2 p2 = *(const float2*)&r[4];
        acc[0] += p0.x; acc[1] += p0.y;
        acc[2] += p1.x; acc[3] += p1.y;
        acc[4] += p2.x; acc[5] += p2.y;
    }

#pragma unroll
    for (int off = 1; off < 8; off <<= 1) {
#pragma unroll
        for (int c = 0; c < F2; c++) acc[c] += __shfl_xor(acc[c], off, 8);
    }

    if (l == 0) {
        float d = dinv[n];
        float y = 0.0f;
#pragma unroll
        for (int c = 0; c < F2; c++) {
            float v = fmaf(acc[c], d, b2[c]);
            v = v > 0.0f ? v : 0.0f;
            float we = Wl[c * 3 + 0] * Wl2[0] + Wl[c * 3 + 1] * Wl2[1] + Wl[c * 3 + 2] * Wl2[2];
            y = fmaf(v, we, y);
        }
        float cnst = bl[0] * Wl2[0] + bl[1] * Wl2[1] + bl[2] * Wl2[2] + bl2[0];
        ynode[n] = y + cnst;
    }
}

// ================= pool: one block per graph, tree reduce + sigmoid ========
__global__ __launch_bounds__(256) void k_pool(const float* __restrict__ ynode,
                                              const int* __restrict__ gs,
                                              float* __restrict__ out, int G) {
    int g = blockIdx.x;
    int s0 = gs[g], e0 = gs[g + 1];
    int t = threadIdx.x;
    float a = 0.0f;
    for (int i = s0 + t; i < e0; i += 256) a += ynode[i];
#pragma unroll
    for (int off = 1; off < 64; off <<= 1) a += __shfl_xor(a, off, 64);
    __shared__ float sm[4];
    if ((t & 63) == 0) sm[t >> 6] = a;
    __syncthreads();
    if (t == 0) {
        float tot = sm[0] + sm[1] + sm[2] + sm[3];
        out[g] = 1.0f / (1.0f + expf(-tot));
    }
}

extern "C" void kernel_launch(void* const* d_in, const int* in_sizes, int n_in,
                              void* d_out, int out_size, void* d_ws, size_t ws_size,
                              hipStream_t stream) {
    const float* x     = (const float*)d_in[0];
    const int*   ei    = (const int*)d_in[1];
    const int*   batch = (const int*)d_in[2];
    const float* W1    = (const float*)d_in[3];
    const float* b1    = (const float*)d_in[4];
    const float* W2    = (const float*)d_in[5];
    const float* b2    = (const float*)d_in[6];
    const float* Wl    = (const float*)d_in[7];
    const float* bl    = (const float*)d_in[8];
    const float* Wl2   = (const float*)d_in[9];
    const float* bl2   = (const float*)d_in[10];
    float* out = (float*)d_out;

    int N = in_sizes[0] / F0;   // 50000
    int E = in_sizes[1] / 2;    // 512000
    int G = out_size;           // 512
    const int* src = ei;
    const int* dst = ei + E;

    char* ws = (char*)d_ws;
    size_t off = 0;
    auto alloc = [&](size_t bytes) {
        void* p = ws + off;
        off = (off + bytes + 255) & ~(size_t)255;
        return p;
    };
    int*   counts    = (int*)alloc((size_t)(N + 1) * 4);  // [N] = total counter
    int*   row_start = (int*)alloc((size_t)N * 4);
    int*   cursor    = (int*)alloc((size_t)N * 4);
    float* dinv      = (float*)alloc((size_t)N * 4);
    int*   ssrc      = (int*)alloc((size_t)E * 4);
    unsigned short* h1a = (unsigned short*)alloc((size_t)N * 64 * 2);  // 128B rows
    unsigned short* h1t = (unsigned short*)alloc((size_t)N * 4 * 2);   // tail cols
    float* h2p       = (float*)alloc((size_t)N * F2 * 4);
    float* ynode     = (float*)alloc((size_t)N * 4);
    int*   gs        = (int*)alloc((size_t)(G + 1) * 4);
    unsigned short* Wb = (unsigned short*)alloc((size_t)NP * KP * 2);

    const int B = 256;
    int nScanBlocks = (N + 1023) / 1024;   // 49

    hipMemsetAsync(counts, 0, (size_t)(N + 1) * 4, stream);
    k_hist<<<(E + B - 1) / B, B, 0, stream>>>(dst, counts, E);
    k_misc<<<(N + B - 1) / B, B, 0, stream>>>(W1, Wb, batch, gs, N, G);
    k_alloc<<<nScanBlocks, 256, 0, stream>>>(counts, row_start, cursor, dinv, counts + N, N);
    k_scatter<<<(E + B - 1) / B, B, 0, stream>>>(src, dst, cursor, ssrc, E);
    k_lin1<<<(N + 63) / 64, 256, 0, stream>>>(x, Wb, dinv, h1a, h1t, N);
    k_gather1_lin2<<<2048, 256, 0, stream>>>(h1a, h1t, dinv, row_start, counts, ssrc,
                                             b1, W2, h2p, N);
    k_gather2<<<((N * 8) + B - 1) / B, B, 0, stream>>>(h2p, dinv, row_start, counts, ssrc,
                                                       b2, Wl, bl, Wl2, bl2, ynode, N);
    k_pool<<<G, 256, 0, stream>>>(ynode, gs, out, G);
}

// Round 12
// 135.901 us; speedup vs baseline: 1.2148x; 1.0085x over previous
//
#include <hip/hip_runtime.h>
#include <math.h>

#define F0 136
#define F1 68
#define F2 6
#define KP 160   // K padded to 5*32
#define NP 80    // N padded to 5*16

typedef __attribute__((ext_vector_type(8))) short short8v;
typedef __attribute__((ext_vector_type(4))) float f32x4;

__device__ inline float bf2f(unsigned short u) {
    union { unsigned int i; float f; } v; v.i = ((unsigned int)u) << 16; return v.f;
}
__device__ inline unsigned short f2bf(float f) {
    union { float f; unsigned int i; } v; v.f = f;
    unsigned int r = v.i + 0x7FFFu + ((v.i >> 16) & 1u);  // round-nearest-even
    return (unsigned short)(r >> 16);
}

// ================= in-degree histogram over dst =================
__global__ void k_hist(const int* __restrict__ dst, int* __restrict__ counts, int E) {
    int e = blockIdx.x * blockDim.x + threadIdx.x;
    if (e < E) atomicAdd(&counts[dst[e]], 1);
}

// ===== fused small prep: W1->bf16 col-major padded  +  graph segments =====
__global__ void k_misc(const float* __restrict__ W1, unsigned short* __restrict__ Wb,
                       const int* __restrict__ batch, int* __restrict__ gs, int N, int G) {
    int i = blockIdx.x * blockDim.x + threadIdx.x;
    if (i < NP * KP) {
        int c = i / KP, k = i - c * KP;
        float v = (c < F1 && k < F0) ? W1[k * F1 + c] : 0.0f;
        Wb[c * KP + k] = f2bf(v);
    }
    if (i < N) {
        int bi = batch[i];
        int bp = (i == 0) ? -1 : batch[i - 1];
        for (int g = bp + 1; g <= bi; g++) gs[g] = i;
        if (i == N - 1) {
            for (int g = bi + 1; g <= G; g++) gs[g] = N;
        }
    }
}

// ===== alloc: block-local scan + atomic block offset (ranges unordered) ====
__global__ __launch_bounds__(256) void k_alloc(const int* __restrict__ counts,
                                               int* __restrict__ row_start,
                                               int* __restrict__ cursor,
                                               float* __restrict__ dinv,
                                               int* __restrict__ total, int N) {
    __shared__ int s[256];
    __shared__ int sbase;
    int t = threadIdx.x;
    int base = blockIdx.x * 1024 + t * 4;
    int v[4], sum = 0;
#pragma unroll
    for (int u = 0; u < 4; u++) {
        int idx = base + u;
        v[u] = (idx < N) ? counts[idx] : 0;
        if (idx < N) dinv[idx] = rsqrtf((float)v[u] + 1.0f);  // self loop
        sum += v[u];
    }
    s[t] = sum;
    __syncthreads();
    for (int off = 1; off < 256; off <<= 1) {
        int y = (t >= off) ? s[t - off] : 0;
        __syncthreads();
        s[t] += y;
        __syncthreads();
    }
    if (t == 255) sbase = atomicAdd(total, s[255]);
    __syncthreads();
    int threadExcl = sbase + s[t] - sum;
    int run = 0;
#pragma unroll
    for (int u = 0; u < 4; u++) {
        int idx = base + u;
        if (idx < N) { row_start[idx] = threadExcl + run; cursor[idx] = threadExcl + run; }
        run += v[u];
    }
}

// ================= scatter edges into CSR (by dst), src index only =========
__global__ void k_scatter(const int* __restrict__ src, const int* __restrict__ dst,
                          int* __restrict__ cursor, int* __restrict__ ssrc, int E) {
    int e = blockIdx.x * blockDim.x + threadIdx.x;
    if (e >= E) return;
    int s = src[e], d = dst[e];
    int pos = atomicAdd(&cursor[d], 1);
    ssrc[pos] = s;
}

// ========== lin1 via MFMA: h1' = (x @ W1) * dinv, bf16, SPLIT layout =======
__global__ __launch_bounds__(256) void k_lin1(const float* __restrict__ x,
                                              const unsigned short* __restrict__ Wb,
                                              const float* __restrict__ dinv,
                                              unsigned short* __restrict__ h1a,
                                              unsigned short* __restrict__ h1t, int N) {
    int tid  = threadIdx.x;
    int lane = tid & 63;
    int w    = tid >> 6;
    int rl   = lane & 15;
    int kg   = lane >> 4;
    int base = blockIdx.x * 64 + w * 16;
    int node = base + rl;
    int nodeClamp = node < N ? node : (N - 1);

    f32x4 acc[5];
#pragma unroll
    for (int t = 0; t < 5; t++) acc[t] = (f32x4){0.f, 0.f, 0.f, 0.f};

#pragma unroll
    for (int kt = 0; kt < 5; kt++) {
        int k0 = kt * 32 + kg * 8;
        short8v a;
        if (k0 < F0) {
            const float* xr = x + (size_t)nodeClamp * F0 + k0;
            float4 lo = *(const float4*)xr;
            float4 hi = *(const float4*)(xr + 4);
            a[0] = (short)f2bf(lo.x); a[1] = (short)f2bf(lo.y);
            a[2] = (short)f2bf(lo.z); a[3] = (short)f2bf(lo.w);
            a[4] = (short)f2bf(hi.x); a[5] = (short)f2bf(hi.y);
            a[6] = (short)f2bf(hi.z); a[7] = (short)f2bf(hi.w);
        } else {
            a = (short8v){0, 0, 0, 0, 0, 0, 0, 0};
        }
#pragma unroll
        for (int nt = 0; nt < 5; nt++) {
            int col = nt * 16 + rl;
            short8v b = *(const short8v*)&Wb[col * KP + k0];
            acc[nt] = __builtin_amdgcn_mfma_f32_16x16x32_bf16(a, b, acc[nt], 0, 0, 0);
        }
    }

    int orow0 = base + kg * 4;
    float dv[4];
#pragma unroll
    for (int j = 0; j < 4; j++) {
        int nr = orow0 + j;
        dv[j] = (nr < N) ? dinv[nr] : 0.0f;
    }
#pragma unroll
    for (int nt = 0; nt < 4; nt++) {   // cols 0..63 -> h1a
        int col = nt * 16 + rl;
#pragma unroll
        for (int j = 0; j < 4; j++) {
            int nr = orow0 + j;
            if (nr < N) h1a[(size_t)nr * 64 + col] = f2bf(acc[nt][j] * dv[j]);
        }
    }
    {   // cols 64..67 -> h1t
        int col = 64 + rl;
        if (col < F1) {
#pragma unroll
            for (int j = 0; j < 4; j++) {
                int nr = orow0 + j;
                if (nr < N) h1t[(size_t)nr * 4 + rl] = f2bf(acc[4][j] * dv[j]);
            }
        }
    }
}

// predicated 8-chunk gather-accumulate from h1a
#define CHUNK8(IDXV, U0, REM, ACC)                                              \
    {                                                                           \
        int s_[8]; float a_[8];                                                 \
        _Pragma("unroll")                                                       \
        for (int u = 0; u < 8; u++) {                                           \
            int uu = (u < (REM)) ? ((U0) + u) : (U0);                           \
            s_[u] = __shfl((IDXV), uu, 64);                                     \
        }                                                                       \
        _Pragma("unroll")                                                       \
        for (int u = 0; u < 8; u++) a_[u] = bf2f(h1a[(size_t)s_[u] * 64 + lane]); \
        _Pragma("unroll")                                                       \
        for (int u = 0; u < 8; u++) (ACC) += (u < (REM)) ? a_[u] : 0.0f;        \
    }

// tail cols 64..67: 16 edges per instruction
#define TAIL16(IDXV, WLEN, ACCT)                                                \
    for (int e0 = 0; e0 < (WLEN); e0 += 16) {                                   \
        int ee = e0 + (lane >> 2);                                              \
        bool val = ee < (WLEN);                                                 \
        int s_ = __shfl((IDXV), val ? ee : 0, 64);                              \
        float tv = bf2f(h1t[(size_t)s_ * 4 + (lane & 3)]);                      \
        (ACCT) += val ? tv : 0.0f;                                              \
    }

// ===== fused: agg1 gather + bias/relu + @W2, persistent, DUAL-NODE pipeline =
// 2048 blocks x 4 waves = 8192 waves (full residency). Per wave: metadata for
// all its nodes preloaded lane-parallel; two nodes processed per iteration so
// two gather chains are in flight. W2/b1 in registers. No LDS, no barriers.
__global__ __launch_bounds__(256) void k_gather1_lin2(const unsigned short* __restrict__ h1a,
                                                      const unsigned short* __restrict__ h1t,
                                                      const float* __restrict__ dinv,
                                                      const int* __restrict__ row_start,
                                                      const int* __restrict__ counts,
                                                      const int* __restrict__ ssrc,
                                                      const float* __restrict__ b1,
                                                      const float* __restrict__ W2,
                                                      float* __restrict__ h2p, int N) {
    int lane = threadIdx.x & 63;
    int wid = blockIdx.x * 4 + (threadIdx.x >> 6);
    int nwaves = gridDim.x * 4;   // 8192

    bool hi = lane < (F1 - 64);
    int colhi = 64 + (lane & 3);

    float b1self = b1[lane];
    float b1hi   = b1[colhi];
    float w2s[F2], w2h[F2];
#pragma unroll
    for (int c = 0; c < F2; c++) {
        w2s[c] = W2[lane * F2 + c];
        w2h[c] = W2[colhi * F2 + c];
    }

    int span = N - wid;
    int cnt = span > 0 ? (span + nwaves - 1) / nwaves : 0;   // <= 7

    // lane t (t < cnt) holds metadata for node wid + t*nwaves — single round
    int nlane = wid + lane * nwaves;
    int rs_l = 0, ct_l = 0;
    if (lane < cnt && nlane < N) { rs_l = row_start[nlane]; ct_l = counts[nlane]; }

    for (int t = 0; t < cnt; t += 2) {
        int nA = wid + t * nwaves;
        bool hasB = (t + 1) < cnt;
        int nB = nA + nwaves;

        int jsA = __shfl(rs_l, t, 64);
        int degA = __shfl(ct_l, t, 64);
        int jsB = hasB ? __shfl(rs_l, t + 1, 64) : 0;
        int degB = hasB ? __shfl(ct_l, t + 1, 64) : 0;

        // issue all independent head loads for BOTH nodes up front
        int wlA = degA > 64 ? 64 : degA;
        int wlB = degB > 64 ? 64 : degB;
        int liA = (wlA > 0) ? (lane < wlA ? lane : wlA - 1) : 0;
        int liB = (wlB > 0) ? (lane < wlB ? lane : wlB - 1) : 0;
        int idxA = (wlA > 0) ? ssrc[jsA + liA] : 0;
        int idxB = (hasB && wlB > 0) ? ssrc[jsB + liB] : 0;
        float accA = bf2f(h1a[(size_t)nA * 64 + lane]);
        float accB = hasB ? bf2f(h1a[(size_t)nB * 64 + lane]) : 0.0f;
        float acctA = (lane < 4) ? bf2f(h1t[(size_t)nA * 4 + lane]) : 0.0f;
        float acctB = (hasB && lane < 4) ? bf2f(h1t[(size_t)nB * 4 + lane]) : 0.0f;

        // interleaved gather chunks: two chains in flight
        int mx = wlA > wlB ? wlA : wlB;
        for (int u0 = 0; u0 < mx; u0 += 8) {
            if (u0 < wlA) CHUNK8(idxA, u0, wlA - u0, accA);
            if (u0 < wlB) CHUNK8(idxB, u0, wlB - u0, accB);
        }
        TAIL16(idxA, wlA, acctA);
        if (hasB) TAIL16(idxB, wlB, acctB);

        // rare: degree > 64 — serial extra windows
        for (int w0 = 64; w0 < degA; w0 += 64) {
            int wlen = degA - w0; wlen = wlen > 64 ? 64 : wlen;
            int li = lane < wlen ? lane : wlen - 1;
            int idxv = ssrc[jsA + w0 + li];
            for (int u0 = 0; u0 < wlen; u0 += 8) CHUNK8(idxv, u0, wlen - u0, accA);
            TAIL16(idxv, wlen, acctA);
        }
        if (hasB) {
            for (int w0 = 64; w0 < degB; w0 += 64) {
                int wlen = degB - w0; wlen = wlen > 64 ? 64 : wlen;
                int li = lane < wlen ? lane : wlen - 1;
                int idxv = ssrc[jsB + w0 + li];
                for (int u0 = 0; u0 < wlen; u0 += 8) CHUNK8(idxv, u0, wlen - u0, accB);
                TAIL16(idxv, wlen, acctB);
            }
        }

        // tail-col partial reduce (both nodes, independent chains)
        float acctrA = acctA, acctrB = acctB;
#pragma unroll
        for (int off = 4; off < 64; off <<= 1) {
            acctrA += __shfl_xor(acctrA, off, 64);
            acctrB += __shfl_xor(acctrB, off, 64);
        }

        float dA = dinv[nA];
        float v0A = fmaf(accA, dA, b1self);             v0A = v0A > 0.0f ? v0A : 0.0f;
        float v1A = hi ? fmaf(acctrA, dA, b1hi) : 0.0f; v1A = v1A > 0.0f ? v1A : 0.0f;
        float dB = hasB ? dinv[nB] : 0.0f;
        float v0B = fmaf(accB, dB, b1self);             v0B = v0B > 0.0f ? v0B : 0.0f;
        float v1B = hi ? fmaf(acctrB, dB, b1hi) : 0.0f; v1B = v1B > 0.0f ? v1B : 0.0f;

        float pA[F2], pB[F2];
#pragma unroll
        for (int c = 0; c < F2; c++) {
            pA[c] = v0A * w2s[c] + v1A * w2h[c];
            pB[c] = v0B * w2s[c] + v1B * w2h[c];
        }
#pragma unroll
        for (int off = 1; off < 64; off <<= 1) {
#pragma unroll
            for (int c = 0; c < F2; c++) {
                pA[c] += __shfl_xor(pA[c], off, 64);
                pB[c] += __shfl_xor(pB[c], off, 64);
            }
        }
        if (lane == 0) {
#pragma unroll
            for (int c = 0; c < F2; c++) h2p[(size_t)nA * F2 + c] = pA[c] * dA;
            if (hasB) {
#pragma unroll
                for (int c = 0; c < F2; c++) h2p[(size_t)nB * F2 + c] = pB[c] * dB;
            }
        }
    }
}

// ================= gather2 + bias/relu + head -> ynode (NO atomics) ========
__global__ __launch_bounds__(256) void k_gather2(const float* __restrict__ h2p,
                                                 const float* __restrict__ dinv,
                                                 const int* __restrict__ row_start,
                                                 const int* __restrict__ counts,
                                                 const int* __restrict__ ssrc,
                                                 const float* __restrict__ b2,
                                                 const float* __restrict__ Wl,
                                                 const float* __restrict__ bl,
                                                 const float* __restrict__ Wl2,
                                                 const float* __restrict__ bl2,
                                                 float* __restrict__ ynode, int N) {
    int t = blockIdx.x * blockDim.x + threadIdx.x;
    int n = t >> 3;
    int l = t & 7;
    if (n >= N) return;

    float acc[F2] = {0, 0, 0, 0, 0, 0};
    if (l == 0) {  // self-loop term h2'[n]
        const float* sr = h2p + (size_t)n * F2;
        float2 p0 = *(const float2*)&sr[0];
        float2 p1 = *(const float2*)&sr[2];
        float2 p2 = *(const float2*)&sr[4];
        acc[0] = p0.x; acc[1] = p0.y;
        acc[2] = p1.x; acc[3] = p1.y;
        acc[4] = p2.x; acc[5] = p2.y;
    }

    int js = row_start[n];
    int je = js + counts[n];
    for (int j = js + l; j < je; j += 8) {
        int s = ssrc[j];
        const float* r = h2p + (size_t)s * F2;
        float2 p0 = *(const float2*)&r[0];
        float2 p1 = *(const float2*)&r[2];
        float2 p2 = *(const float2*)&r[4];
        acc[0] += p0.x; acc[1] += p0.y;
        acc[2] += p1.x; acc[3] += p1.y;
        acc[4] += p2.x; acc[5] += p2.y;
    }

#pragma unroll
    for (int off = 1; off < 8; off <<= 1) {
#pragma unroll
        for (int c = 0; c < F2; c++) acc[c] += __shfl_xor(acc[c], off, 8);
    }

    if (l == 0) {
        float d = dinv[n];
        float y = 0.0f;
#pragma unroll
        for (int c = 0; c < F2; c++) {
            float v = fmaf(acc[c], d, b2[c]);
            v = v > 0.0f ? v : 0.0f;
            float we = Wl[c * 3 + 0] * Wl2[0] + Wl[c * 3 + 1] * Wl2[1] + Wl[c * 3 + 2] * Wl2[2];
            y = fmaf(v, we, y);
        }
        float cnst = bl[0] * Wl2[0] + bl[1] * Wl2[1] + bl[2] * Wl2[2] + bl2[0];
        ynode[n] = y + cnst;
    }
}

// ================= pool: one block per graph, tree reduce + sigmoid ========
__global__ __launch_bounds__(256) void k_pool(const float* __restrict__ ynode,
                                              const int* __restrict__ gs,
                                              float* __restrict__ out, int G) {
    int g = blockIdx.x;
    int s0 = gs[g], e0 = gs[g + 1];
    int t = threadIdx.x;
    float a = 0.0f;
    for (int i = s0 + t; i < e0; i += 256) a += ynode[i];
#pragma unroll
    for (int off = 1; off < 64; off <<= 1) a += __shfl_xor(a, off, 64);
    __shared__ float sm[4];
    if ((t & 63) == 0) sm[t >> 6] = a;
    __syncthreads();
    if (t == 0) {
        float tot = sm[0] + sm[1] + sm[2] + sm[3];
        out[g] = 1.0f / (1.0f + expf(-tot));
    }
}

extern "C" void kernel_launch(void* const* d_in, const int* in_sizes, int n_in,
                              void* d_out, int out_size, void* d_ws, size_t ws_size,
                              hipStream_t stream) {
    const float* x     = (const float*)d_in[0];
    const int*   ei    = (const int*)d_in[1];
    const int*   batch = (const int*)d_in[2];
    const float* W1    = (const float*)d_in[3];
    const float* b1    = (const float*)d_in[4];
    const float* W2    = (const float*)d_in[5];
    const float* b2    = (const float*)d_in[6];
    const float* Wl    = (const float*)d_in[7];
    const float* bl    = (const float*)d_in[8];
    const float* Wl2   = (const float*)d_in[9];
    const float* bl2   = (const float*)d_in[10];
    float* out = (float*)d_out;

    int N = in_sizes[0] / F0;   // 50000
    int E = in_sizes[1] / 2;    // 512000
    int G = out_size;           // 512
    const int* src = ei;
    const int* dst = ei + E;

    char* ws = (char*)d_ws;
    size_t off = 0;
    auto alloc = [&](size_t bytes) {
        void* p = ws + off;
        off = (off + bytes + 255) & ~(size_t)255;
        return p;
    };
    int*   counts    = (int*)alloc((size_t)(N + 1) * 4);  // [N] = total counter
    int*   row_start = (int*)alloc((size_t)N * 4);
    int*   cursor    = (int*)alloc((size_t)N * 4);
    float* dinv      = (float*)alloc((size_t)N * 4);
    int*   ssrc      = (int*)alloc((size_t)E * 4);
    unsigned short* h1a = (unsigned short*)alloc((size_t)N * 64 * 2);  // 128B rows
    unsigned short* h1t = (unsigned short*)alloc((size_t)N * 4 * 2);   // tail cols
    float* h2p       = (float*)alloc((size_t)N * F2 * 4);
    float* ynode     = (float*)alloc((size_t)N * 4);
    int*   gs        = (int*)alloc((size_t)(G + 1) * 4);
    unsigned short* Wb = (unsigned short*)alloc((size_t)NP * KP * 2);

    const int B = 256;
    int nScanBlocks = (N + 1023) / 1024;   // 49

    hipMemsetAsync(counts, 0, (size_t)(N + 1) * 4, stream);
    k_hist<<<(E + B - 1) / B, B, 0, stream>>>(dst, counts, E);
    k_misc<<<(N + B - 1) / B, B, 0, stream>>>(W1, Wb, batch, gs, N, G);
    k_alloc<<<nScanBlocks, 256, 0, stream>>>(counts, row_start, cursor, dinv, counts + N, N);
    k_scatter<<<(E + B - 1) / B, B, 0, stream>>>(src, dst, cursor, ssrc, E);
    k_lin1<<<(N + 63) / 64, 256, 0, stream>>>(x, Wb, dinv, h1a, h1t, N);
    k_gather1_lin2<<<2048, 256, 0, stream>>>(h1a, h1t, dinv, row_start, counts, ssrc,
                                             b1, W2, h2p, N);
    k_gather2<<<((N * 8) + B - 1) / B, B, 0, stream>>>(h2p, dinv, row_start, counts, ssrc,
                                                       b2, Wl, bl, Wl2, bl2, ynode, N);
    k_pool<<<G, 256, 0, stream>>>(ynode, gs, out, G);
}

// Round 13
// 122.183 us; speedup vs baseline: 1.3512x; 1.1123x over previous
//
#include <hip/hip_runtime.h>
#include <math.h>

#define F0 136
#define F1 68
#define F2 6
#define KP 160   // lin1 K padded to 5*32
#define NP 80    // lin1 N padded to 5*16
#define K2 96    // lin2 K padded to 3*32

typedef __attribute__((ext_vector_type(8))) short short8v;
typedef __attribute__((ext_vector_type(4))) float f32x4;

__device__ inline float bf2f(unsigned short u) {
    union { unsigned int i; float f; } v; v.i = ((unsigned int)u) << 16; return v.f;
}
__device__ inline unsigned short f2bf(float f) {
    union { float f; unsigned int i; } v; v.f = f;
    unsigned int r = v.i + 0x7FFFu + ((v.i >> 16) & 1u);  // round-nearest-even
    return (unsigned short)(r >> 16);
}

// ================= in-degree histogram over dst =================
__global__ void k_hist(const int* __restrict__ dst, int* __restrict__ counts, int E) {
    int e = blockIdx.x * blockDim.x + threadIdx.x;
    if (e < E) atomicAdd(&counts[dst[e]], 1);
}

// ===== prep: W1->bf16 col-major [80][160]; W2->bf16 col-major [16][96];
// ===== graph segments from sorted batch =====
__global__ void k_misc(const float* __restrict__ W1, unsigned short* __restrict__ Wb,
                       const float* __restrict__ W2, unsigned short* __restrict__ Wb2,
                       const int* __restrict__ batch, int* __restrict__ gs, int N, int G) {
    int i = blockIdx.x * blockDim.x + threadIdx.x;
    if (i < NP * KP) {
        int c = i / KP, k = i - c * KP;
        float v = (c < F1 && k < F0) ? W1[k * F1 + c] : 0.0f;
        Wb[c * KP + k] = f2bf(v);
    }
    if (i < 16 * K2) {
        int c = i / K2, k = i - c * K2;
        float v = (c < F2 && k < F1) ? W2[k * F2 + c] : 0.0f;
        Wb2[c * K2 + k] = f2bf(v);
    }
    if (i < N) {
        int bi = batch[i];
        int bp = (i == 0) ? -1 : batch[i - 1];
        for (int g = bp + 1; g <= bi; g++) gs[g] = i;
        if (i == N - 1) {
            for (int g = bi + 1; g <= G; g++) gs[g] = N;
        }
    }
}

// ===== alloc: row length = indeg+1 (self loop IN CSR); block-scan + atomic
// block offset (row ranges unordered). Writes self-edge, cursor, dinv. =====
__global__ __launch_bounds__(256) void k_alloc(const int* __restrict__ counts,
                                               int* __restrict__ row_start,
                                               int* __restrict__ cursor,
                                               float* __restrict__ dinv,
                                               int* __restrict__ ssrc,
                                               int* __restrict__ total, int N) {
    __shared__ int s[256];
    __shared__ int sbase;
    int t = threadIdx.x;
    int base = blockIdx.x * 1024 + t * 4;
    int v[4], sum = 0;
#pragma unroll
    for (int u = 0; u < 4; u++) {
        int idx = base + u;
        v[u] = (idx < N) ? (counts[idx] + 1) : 0;   // +1 self loop
        if (idx < N) dinv[idx] = rsqrtf((float)v[u]);
        sum += v[u];
    }
    s[t] = sum;
    __syncthreads();
    for (int off = 1; off < 256; off <<= 1) {
        int y = (t >= off) ? s[t - off] : 0;
        __syncthreads();
        s[t] += y;
        __syncthreads();
    }
    if (t == 255) sbase = atomicAdd(total, s[255]);
    __syncthreads();
    int threadExcl = sbase + s[t] - sum;
    int run = 0;
#pragma unroll
    for (int u = 0; u < 4; u++) {
        int idx = base + u;
        if (idx < N) {
            int rs = threadExcl + run;
            row_start[idx] = rs;
            ssrc[rs] = idx;          // self edge at slot 0
            cursor[idx] = rs + 1;    // neighbors go after
        }
        run += v[u];
    }
}

// ================= scatter edges into CSR (by dst), src index only =========
__global__ void k_scatter(const int* __restrict__ src, const int* __restrict__ dst,
                          int* __restrict__ cursor, int* __restrict__ ssrc, int E) {
    int e = blockIdx.x * blockDim.x + threadIdx.x;
    if (e >= E) return;
    int s = src[e], d = dst[e];
    int pos = atomicAdd(&cursor[d], 1);
    ssrc[pos] = s;
}

// ========== lin1 via MFMA: h1' = (x @ W1) * dinv, bf16, SPLIT layout =======
__global__ __launch_bounds__(256) void k_lin1(const float* __restrict__ x,
                                              const unsigned short* __restrict__ Wb,
                                              const float* __restrict__ dinv,
                                              unsigned short* __restrict__ h1a,
                                              unsigned short* __restrict__ h1t, int N) {
    int tid  = threadIdx.x;
    int lane = tid & 63;
    int w    = tid >> 6;
    int rl   = lane & 15;
    int kg   = lane >> 4;
    int base = blockIdx.x * 64 + w * 16;
    int node = base + rl;
    int nodeClamp = node < N ? node : (N - 1);

    f32x4 acc[5];
#pragma unroll
    for (int t = 0; t < 5; t++) acc[t] = (f32x4){0.f, 0.f, 0.f, 0.f};

#pragma unroll
    for (int kt = 0; kt < 5; kt++) {
        int k0 = kt * 32 + kg * 8;
        short8v a;
        if (k0 < F0) {
            const float* xr = x + (size_t)nodeClamp * F0 + k0;
            float4 lo = *(const float4*)xr;
            float4 hi = *(const float4*)(xr + 4);
            a[0] = (short)f2bf(lo.x); a[1] = (short)f2bf(lo.y);
            a[2] = (short)f2bf(lo.z); a[3] = (short)f2bf(lo.w);
            a[4] = (short)f2bf(hi.x); a[5] = (short)f2bf(hi.y);
            a[6] = (short)f2bf(hi.z); a[7] = (short)f2bf(hi.w);
        } else {
            a = (short8v){0, 0, 0, 0, 0, 0, 0, 0};
        }
#pragma unroll
        for (int nt = 0; nt < 5; nt++) {
            int col = nt * 16 + rl;
            short8v b = *(const short8v*)&Wb[col * KP + k0];
            acc[nt] = __builtin_amdgcn_mfma_f32_16x16x32_bf16(a, b, acc[nt], 0, 0, 0);
        }
    }

    int orow0 = base + kg * 4;
    float dv[4];
#pragma unroll
    for (int j = 0; j < 4; j++) {
        int nr = orow0 + j;
        dv[j] = (nr < N) ? dinv[nr] : 0.0f;
    }
#pragma unroll
    for (int nt = 0; nt < 4; nt++) {   // cols 0..63 -> h1a
        int col = nt * 16 + rl;
#pragma unroll
        for (int j = 0; j < 4; j++) {
            int nr = orow0 + j;
            if (nr < N) h1a[(size_t)nr * 64 + col] = f2bf(acc[nt][j] * dv[j]);
        }
    }
    {   // cols 64..67 -> h1t
        int col = 64 + rl;
        if (col < F1) {
#pragma unroll
            for (int j = 0; j < 4; j++) {
                int nr = orow0 + j;
                if (nr < N) h1t[(size_t)nr * 4 + rl] = f2bf(acc[4][j] * dv[j]);
            }
        }
    }
}

// predicated 8-chunk gather-accumulate from h1a
#define CHUNK8(IDXV, U0, REM, ACC)                                              \
    {                                                                           \
        int s_[8]; float a_[8];                                                 \
        _Pragma("unroll")                                                       \
        for (int u = 0; u < 8; u++) {                                           \
            int uu = (u < (REM)) ? ((U0) + u) : (U0);                           \
            s_[u] = __shfl((IDXV), uu, 64);                                     \
        }                                                                       \
        _Pragma("unroll")                                                       \
        for (int u = 0; u < 8; u++) a_[u] = bf2f(h1a[(size_t)s_[u] * 64 + lane]); \
        _Pragma("unroll")                                                       \
        for (int u = 0; u < 8; u++) (ACC) += (u < (REM)) ? a_[u] : 0.0f;        \
    }

// tail cols 64..67: 16 edges per instruction
#define TAIL16(IDXV, WLEN, ACCT)                                                \
    for (int e0 = 0; e0 < (WLEN); e0 += 16) {                                   \
        int ee = e0 + (lane >> 2);                                              \
        bool val = ee < (WLEN);                                                 \
        int s_ = __shfl((IDXV), val ? ee : 0, 64);                              \
        float tv = bf2f(h1t[(size_t)s_ * 4 + (lane & 3)]);                      \
        (ACCT) += val ? tv : 0.0f;                                              \
    }

// ===== gather1: agg1 + bias + relu -> z (bf16, split layout). NO reduce. ====
// Persistent: 2048 blocks x 4 waves. Dual-node pipeline. Self edge is in CSR.
__global__ __launch_bounds__(256) void k_gather1(const unsigned short* __restrict__ h1a,
                                                 const unsigned short* __restrict__ h1t,
                                                 const float* __restrict__ dinv,
                                                 const int* __restrict__ row_start,
                                                 const int* __restrict__ counts,
                                                 const int* __restrict__ ssrc,
                                                 const float* __restrict__ b1,
                                                 unsigned short* __restrict__ za,
                                                 unsigned short* __restrict__ zt, int N) {
    int lane = threadIdx.x & 63;
    int wid = blockIdx.x * 4 + (threadIdx.x >> 6);
    int nwaves = gridDim.x * 4;   // 8192

    float b1self = b1[lane];
    float b1hi   = b1[64 + (lane & 3)];

    int span = N - wid;
    int cnt = span > 0 ? (span + nwaves - 1) / nwaves : 0;   // <= 7

    // lane t holds metadata for node wid + t*nwaves — one parallel round
    int nlane = wid + lane * nwaves;
    int rs_l = 0, ct_l = 0; float dv_l = 0.0f;
    if (lane < cnt && nlane < N) {
        rs_l = row_start[nlane]; ct_l = counts[nlane]; dv_l = dinv[nlane];
    }

    for (int t = 0; t < cnt; t += 2) {
        int nA = wid + t * nwaves;
        bool hasB = (t + 1) < cnt;
        int nB = nA + nwaves;

        int jsA = __shfl(rs_l, t, 64);
        int degA = __shfl(ct_l, t, 64) + 1;          // +1 self edge
        float dA = __shfl(dv_l, t, 64);
        int jsB = hasB ? __shfl(rs_l, t + 1, 64) : 0;
        int degB = hasB ? __shfl(ct_l, t + 1, 64) + 1 : 0;
        float dB = hasB ? __shfl(dv_l, t + 1, 64) : 0.0f;

        int wlA = degA > 64 ? 64 : degA;
        int wlB = degB > 64 ? 64 : degB;
        int liA = lane < wlA ? lane : wlA - 1;
        int liB = (wlB > 0) ? (lane < wlB ? lane : wlB - 1) : 0;
        int idxA = ssrc[jsA + liA];
        int idxB = hasB ? ssrc[jsB + liB] : 0;

        float accA = 0.0f, accB = 0.0f, acctA = 0.0f, acctB = 0.0f;

        int mx = wlA > wlB ? wlA : wlB;
        for (int u0 = 0; u0 < mx; u0 += 8) {
            if (u0 < wlA) CHUNK8(idxA, u0, wlA - u0, accA);
            if (u0 < wlB) CHUNK8(idxB, u0, wlB - u0, accB);
        }
        TAIL16(idxA, wlA, acctA);
        if (hasB) TAIL16(idxB, wlB, acctB);

        // rare: degree > 64 — serial extra windows
        for (int w0 = 64; w0 < degA; w0 += 64) {
            int wlen = degA - w0; wlen = wlen > 64 ? 64 : wlen;
            int li = lane < wlen ? lane : wlen - 1;
            int idxv = ssrc[jsA + w0 + li];
            for (int u0 = 0; u0 < wlen; u0 += 8) CHUNK8(idxv, u0, wlen - u0, accA);
            TAIL16(idxv, wlen, acctA);
        }
        if (hasB) {
            for (int w0 = 64; w0 < degB; w0 += 64) {
                int wlen = degB - w0; wlen = wlen > 64 ? 64 : wlen;
                int li = lane < wlen ? lane : wlen - 1;
                int idxv = ssrc[jsB + w0 + li];
                for (int u0 = 0; u0 < wlen; u0 += 8) CHUNK8(idxv, u0, wlen - u0, accB);
                TAIL16(idxv, wlen, acctB);
            }
        }

        // only the 4 tail cols need a cross-lane reduce (4 steps)
        float atrA = acctA, atrB = acctB;
#pragma unroll
        for (int off = 4; off < 64; off <<= 1) {
            atrA += __shfl_xor(atrA, off, 64);
            atrB += __shfl_xor(atrB, off, 64);
        }

        float v0A = fmaf(accA, dA, b1self);  v0A = v0A > 0.0f ? v0A : 0.0f;
        za[(size_t)nA * 64 + lane] = f2bf(v0A);               // coalesced 128B store
        float vtA = fmaf(atrA, dA, b1hi);    vtA = vtA > 0.0f ? vtA : 0.0f;
        if (lane < 4) zt[(size_t)nA * 4 + lane] = f2bf(vtA);

        if (hasB) {
            float v0B = fmaf(accB, dB, b1self);  v0B = v0B > 0.0f ? v0B : 0.0f;
            za[(size_t)nB * 64 + lane] = f2bf(v0B);
            float vtB = fmaf(atrB, dB, b1hi);    vtB = vtB > 0.0f ? vtB : 0.0f;
            if (lane < 4) zt[(size_t)nB * 4 + lane] = f2bf(vtB);
        }
    }
}

// ========== lin2 via MFMA: h2p = (z @ W2) * dinv, fp32 [N][6] ==========
__global__ __launch_bounds__(256) void k_lin2(const unsigned short* __restrict__ za,
                                              const unsigned short* __restrict__ zt,
                                              const unsigned short* __restrict__ Wb2,
                                              const float* __restrict__ dinv,
                                              float* __restrict__ h2p, int N) {
    int tid  = threadIdx.x;
    int lane = tid & 63;
    int w    = tid >> 6;
    int rl   = lane & 15;
    int kg   = lane >> 4;
    int base = blockIdx.x * 64 + w * 16;
    int node = base + rl;
    int nodeClamp = node < N ? node : (N - 1);

    f32x4 acc = (f32x4){0.f, 0.f, 0.f, 0.f};
#pragma unroll
    for (int kt = 0; kt < 3; kt++) {
        int k0 = kt * 32 + kg * 8;
        short8v a;
        if (k0 < 64) {
            a = *(const short8v*)&za[(size_t)nodeClamp * 64 + k0];
        } else if (k0 == 64) {
            const unsigned short* tr = &zt[(size_t)nodeClamp * 4];
            a[0] = (short)tr[0]; a[1] = (short)tr[1];
            a[2] = (short)tr[2]; a[3] = (short)tr[3];
            a[4] = 0; a[5] = 0; a[6] = 0; a[7] = 0;
        } else {
            a = (short8v){0, 0, 0, 0, 0, 0, 0, 0};
        }
        short8v b = *(const short8v*)&Wb2[rl * K2 + k0];
        acc = __builtin_amdgcn_mfma_f32_16x16x32_bf16(a, b, acc, 0, 0, 0);
    }

    if (rl < F2) {
        int orow0 = base + kg * 4;
#pragma unroll
        for (int j = 0; j < 4; j++) {
            int nr = orow0 + j;
            if (nr < N) h2p[(size_t)nr * F2 + rl] = acc[j] * dinv[nr];
        }
    }
}

// ====== gather2 + bias/relu + head -> ynode (self edge in CSR, no atomics) ==
__global__ __launch_bounds__(256) void k_gather2(const float* __restrict__ h2p,
                                                 const float* __restrict__ dinv,
                                                 const int* __restrict__ row_start,
                                                 const int* __restrict__ counts,
                                                 const int* __restrict__ ssrc,
                                                 const float* __restrict__ b2,
                                                 const float* __restrict__ Wl,
                                                 const float* __restrict__ bl,
                                                 const float* __restrict__ Wl2,
                                                 const float* __restrict__ bl2,
                                                 float* __restrict__ ynode, int N) {
    int t = blockIdx.x * blockDim.x + threadIdx.x;
    int n = t >> 3;
    int l = t & 7;
    if (n >= N) return;

    float acc[F2] = {0, 0, 0, 0, 0, 0};
    int js = row_start[n];
    int je = js + counts[n] + 1;   // incl self edge
    for (int j = js + l; j < je; j += 8) {
        int s = ssrc[j];
        const float* r = h2p + (size_t)s * F2;
        float2 p0 = *(const float2*)&r[0];
        float2 p1 = *(const float2*)&r[2];
        float2 p2 = *(const float2*)&r[4];
        acc[0] += p0.x; acc[1] += p0.y;
        acc[2] += p1.x; acc[3] += p1.y;
        acc[4] += p2.x; acc[5] += p2.y;
    }

#pragma unroll
    for (int off = 1; off < 8; off <<= 1) {
#pragma unroll
        for (int c = 0; c < F2; c++) acc[c] += __shfl_xor(acc[c], off, 8);
    }

    if (l == 0) {
        float d = dinv[n];
        float y = 0.0f;
#pragma unroll
        for (int c = 0; c < F2; c++) {
            float v = fmaf(acc[c], d, b2[c]);
            v = v > 0.0f ? v : 0.0f;
            float we = Wl[c * 3 + 0] * Wl2[0] + Wl[c * 3 + 1] * Wl2[1] + Wl[c * 3 + 2] * Wl2[2];
            y = fmaf(v, we, y);
        }
        float cnst = bl[0] * Wl2[0] + bl[1] * Wl2[1] + bl[2] * Wl2[2] + bl2[0];
        ynode[n] = y + cnst;
    }
}

// ================= pool: one block per graph, tree reduce + sigmoid ========
__global__ __launch_bounds__(256) void k_pool(const float* __restrict__ ynode,
                                              const int* __restrict__ gs,
                                              float* __restrict__ out, int G) {
    int g = blockIdx.x;
    int s0 = gs[g], e0 = gs[g + 1];
    int t = threadIdx.x;
    float a = 0.0f;
    for (int i = s0 + t; i < e0; i += 256) a += ynode[i];
#pragma unroll
    for (int off = 1; off < 64; off <<= 1) a += __shfl_xor(a, off, 64);
    __shared__ float sm[4];
    if ((t & 63) == 0) sm[t >> 6] = a;
    __syncthreads();
    if (t == 0) {
        float tot = sm[0] + sm[1] + sm[2] + sm[3];
        out[g] = 1.0f / (1.0f + expf(-tot));
    }
}

extern "C" void kernel_launch(void* const* d_in, const int* in_sizes, int n_in,
                              void* d_out, int out_size, void* d_ws, size_t ws_size,
                              hipStream_t stream) {
    const float* x     = (const float*)d_in[0];
    const int*   ei    = (const int*)d_in[1];
    const int*   batch = (const int*)d_in[2];
    const float* W1    = (const float*)d_in[3];
    const float* b1    = (const float*)d_in[4];
    const float* W2    = (const float*)d_in[5];
    const float* b2    = (const float*)d_in[6];
    const float* Wl    = (const float*)d_in[7];
    const float* bl    = (const float*)d_in[8];
    const float* Wl2   = (const float*)d_in[9];
    const float* bl2   = (const float*)d_in[10];
    float* out = (float*)d_out;

    int N = in_sizes[0] / F0;   // 50000
    int E = in_sizes[1] / 2;    // 512000
    int G = out_size;           // 512
    const int* src = ei;
    const int* dst = ei + E;

    char* ws = (char*)d_ws;
    size_t off = 0;
    auto alloc = [&](size_t bytes) {
        void* p = ws + off;
        off = (off + bytes + 255) & ~(size_t)255;
        return p;
    };
    int*   counts    = (int*)alloc((size_t)(N + 1) * 4);       // [N] = total counter
    int*   row_start = (int*)alloc((size_t)N * 4);
    int*   cursor    = (int*)alloc((size_t)N * 4);
    float* dinv      = (float*)alloc((size_t)N * 4);
    int*   ssrc      = (int*)alloc((size_t)(E + N) * 4);       // incl self edges
    unsigned short* h1a = (unsigned short*)alloc((size_t)N * 64 * 2);
    unsigned short* h1t = (unsigned short*)alloc((size_t)N * 4 * 2);
    unsigned short* za  = (unsigned short*)alloc((size_t)N * 64 * 2);
    unsigned short* zt  = (unsigned short*)alloc((size_t)N * 4 * 2);
    float* h2p       = (float*)alloc((size_t)N * F2 * 4);
    float* ynode     = (float*)alloc((size_t)N * 4);
    int*   gs        = (int*)alloc((size_t)(G + 1) * 4);
    unsigned short* Wb  = (unsigned short*)alloc((size_t)NP * KP * 2);
    unsigned short* Wb2 = (unsigned short*)alloc((size_t)16 * K2 * 2);

    const int B = 256;
    int nScanBlocks = (N + 1023) / 1024;   // 49

    hipMemsetAsync(counts, 0, (size_t)(N + 1) * 4, stream);
    k_hist<<<(E + B - 1) / B, B, 0, stream>>>(dst, counts, E);
    k_misc<<<(N + B - 1) / B, B, 0, stream>>>(W1, Wb, W2, Wb2, batch, gs, N, G);
    k_alloc<<<nScanBlocks, 256, 0, stream>>>(counts, row_start, cursor, dinv, ssrc, counts + N, N);
    k_scatter<<<(E + B - 1) / B, B, 0, stream>>>(src, dst, cursor, ssrc, E);
    k_lin1<<<(N + 63) / 64, 256, 0, stream>>>(x, Wb, dinv, h1a, h1t, N);
    k_gather1<<<2048, 256, 0, stream>>>(h1a, h1t, dinv, row_start, counts, ssrc, b1, za, zt, N);
    k_lin2<<<(N + 63) / 64, 256, 0, stream>>>(za, zt, Wb2, dinv, h2p, N);
    k_gather2<<<((N * 8) + B - 1) / B, B, 0, stream>>>(h2p, dinv, row_start, counts, ssrc,
                                                       b2, Wl, bl, Wl2, bl2, ynode, N);
    k_pool<<<G, 256, 0, stream>>>(ynode, gs, out, G);
}